// Round 7
// baseline (218.345 us; speedup 1.0000x reference)
//
#include <hip/hip_runtime.h>
#include <stdint.h>

#define D_MODEL 1024
#define D_STATE 16
#define BB 4
#define TT 2048
#define MM (BB*TT)       /* 8192 rows */
#define NCH 64           /* time chunks */
#define CL (TT/NCH)      /* 32 steps per chunk */

typedef __attribute__((ext_vector_type(4))) float f32x4;
typedef __attribute__((ext_vector_type(8))) short short8;

__device__ __forceinline__ unsigned short f2bf(float f) {
  union { float f; uint32_t u; } v; v.f = f;
  uint32_t r = v.u + 0x7FFFu + ((v.u >> 16) & 1u);   // RNE
  return (unsigned short)(r >> 16);
}

__device__ __forceinline__ float softplusf(float v) {
  return v > 20.f ? v : log1pf(expf(v));
}

__device__ __forceinline__ f32x4 splat4(float s) {
  f32x4 r; r[0]=s; r[1]=s; r[2]=s; r[3]=s; return r;
}
__device__ __forceinline__ f32x4 exp2v4(f32x4 v) {
  f32x4 r;
  r[0]=__builtin_amdgcn_exp2f(v[0]);
  r[1]=__builtin_amdgcn_exp2f(v[1]);
  r[2]=__builtin_amdgcn_exp2f(v[2]);
  r[3]=__builtin_amdgcn_exp2f(v[3]);
  return r;
}

// ---------------- f32 -> bf16 conversion (float4 vectorized) ----------------
__global__ __launch_bounds__(256) void cvt_bf16_kernel(
    const float* __restrict__ in, unsigned short* __restrict__ out, int n4)
{
  const float4* in4 = (const float4*)in;
  ushort4* out4 = (ushort4*)out;
  int i = blockIdx.x * blockDim.x + threadIdx.x;
  const int stride = gridDim.x * blockDim.x;
  for (; i < n4; i += stride) {
    float4 v = in4[i];
    ushort4 o;
    o.x = f2bf(v.x); o.y = f2bf(v.y); o.z = f2bf(v.z); o.w = f2bf(v.w);
    out4[i] = o;
  }
}

// ---------------- precompute c2[e][s] = -(softplus(a_log)+1e-4)*log2e -------
__global__ __launch_bounds__(256) void prep_c2_kernel(
    const float* __restrict__ a_log, float* __restrict__ c2tab, int n)
{
  int i = blockIdx.x * 256 + threadIdx.x;
  if (i < n) {
    const float ap = softplusf(a_log[i]) + 1e-4f;
    c2tab[i] = -ap * 1.44269504088896f;
  }
}

__device__ __forceinline__ void glds16(const char* g, char* l) {
  __builtin_amdgcn_global_load_lds(
      (const __attribute__((address_space(1))) void*)g,
      (__attribute__((address_space(3))) void*)l, 16, 0, 0);
}

// ---------------- bf16 GEMM, B-stationary: C[m][n] = sum_k A[m][k]*B[n][k] --
// Block = 512 thr (8 waves), output 512x32. B panel (1024K x 32N) lives in
// LDS as 64 fragment-ordered 1KB chunks (chunk c = kc*2+nf; lane l holds
// B[bn+nf*16+(l&15)][kc*32+(l>>4)*8..+7]), staged ONCE via global_load_lds
// (per-lane global source, wave-uniform LDS dest) -> one barrier total.
// K-loop is BARRIER-FREE: A fragments go global->VGPR directly (per-lane
// short8 loads), B fragments are conflict-free ds_read_b128 (chunk+lane*16).
// Waves drift independently; 2 blocks/CU x 8 waves = 4 waves/SIMD hide the
// load latency. Compiler owns all waitcnts (register dataflow).
template<bool SOFTPLUS>
__global__ __launch_bounds__(512, 4) void gemm_bs_kernel(
    const unsigned short* __restrict__ A,   // M x K bf16 (row-major)
    const unsigned short* __restrict__ Bm,  // N x K bf16 (row-major, i.e. B^T)
    const float* __restrict__ bias,         // N
    float* __restrict__ C,                  // M x N f32
    int M, int N, int K)
{
  __shared__ __align__(16) unsigned short Blds[64*512];   // 64 KB

  const int tid  = threadIdx.x;
  const int lane = tid & 63;
  const int w    = tid >> 6;          // wave 0..7
  const int r16  = lane & 15, kh = lane >> 4;
  const int khb  = kh * 16;

  // XCD swizzle: consecutive newid share bm -> each XCD L2 holds 2 A-panels
  // (2MB) + B (2MB). nwg = (M/512)*(N/32) = 512, divisible by 8.
  const int nwg   = gridDim.x;
  const int flat  = blockIdx.x;
  const int newid = (flat & 7) * (nwg >> 3) + (flat >> 3);
  const int bm    = (newid >> 5) * 512;
  const int bn    = (newid & 31) * 32;

  // ---- stage B panel once: wave w stages chunks w*8 .. w*8+7 ----
  #pragma unroll
  for (int r = 0; r < 8; ++r) {
    const int c  = w*8 + r;
    const int kc = c >> 1, nf = c & 1;
    const char* gb = (const char*)Bm
        + ((size_t)(bn + nf*16 + r16) * K + kc*32) * 2 + khb;
    glds16(gb, (char*)Blds + c*1024);
  }
  asm volatile("s_waitcnt vmcnt(0)" ::: "memory");  // own B loads landed
  __builtin_amdgcn_s_barrier();                     // whole panel visible

  // ---- per-lane A fragment base pointers (wave-private rows) ----
  const char* pa[4];
  #pragma unroll
  for (int m = 0; m < 4; ++m)
    pa[m] = (const char*)A + ((size_t)(bm + w*64 + m*16 + r16) * K) * 2 + khb;

  f32x4 acc[4][2] = {};
  const int NT = K >> 5;    // 32
  const char* Bbase = (const char*)Blds + lane*16;

  short8 a0[4], a1[4];
  #pragma unroll
  for (int m = 0; m < 4; ++m) a0[m] = *(const short8*)(pa[m]);

  for (int i = 0; i < NT; i += 2) {
    // prefetch iter i+1 while computing iter i
    #pragma unroll
    for (int m = 0; m < 4; ++m) a1[m] = *(const short8*)(pa[m] + (i+1)*64);
    {
      short8 b0 = *(const short8*)(Bbase + (i*2+0)*1024);
      short8 b1 = *(const short8*)(Bbase + (i*2+1)*1024);
      #pragma unroll
      for (int m = 0; m < 4; ++m) {
        acc[m][0] = __builtin_amdgcn_mfma_f32_16x16x32_bf16(a0[m], b0, acc[m][0], 0, 0, 0);
        acc[m][1] = __builtin_amdgcn_mfma_f32_16x16x32_bf16(a0[m], b1, acc[m][1], 0, 0, 0);
      }
    }
    // prefetch iter i+2 while computing iter i+1
    if (i + 2 < NT) {
      #pragma unroll
      for (int m = 0; m < 4; ++m) a0[m] = *(const short8*)(pa[m] + (i+2)*64);
    }
    {
      short8 b0 = *(const short8*)(Bbase + (i*2+2)*1024);
      short8 b1 = *(const short8*)(Bbase + (i*2+3)*1024);
      #pragma unroll
      for (int m = 0; m < 4; ++m) {
        acc[m][0] = __builtin_amdgcn_mfma_f32_16x16x32_bf16(a1[m], b0, acc[m][0], 0, 0, 0);
        acc[m][1] = __builtin_amdgcn_mfma_f32_16x16x32_bf16(a1[m], b1, acc[m][1], 0, 0, 0);
      }
    }
  }

  // epilogue: row = bm + w*64 + m*16 + kh*4 + j ; col = bn + nf*16 + r16
  #pragma unroll
  for (int nf = 0; nf < 2; ++nf) {
    const int col = bn + nf*16 + r16;
    const float bv = bias[col];
    #pragma unroll
    for (int m = 0; m < 4; ++m) {
      #pragma unroll
      for (int j = 0; j < 4; ++j) {
        const int row = bm + w*64 + m*16 + kh*4 + j;
        float v = acc[m][nf][j] + bv;
        if (SOFTPLUS) v = softplusf(v);
        C[(size_t)row*N + col] = v;
      }
    }
  }
}

// ---------------- scan pass 1: per-chunk local state L and sum(dt) ----------
__global__ __launch_bounds__(256) void scan_pass1_kernel(
    const float* __restrict__ x, const float* __restrict__ delta,
    const float* __restrict__ c2tab,
    float* __restrict__ Lc, float* __restrict__ dts_out)
{
  const int e  = blockIdx.x * 256 + threadIdx.x;
  const int b  = blockIdx.y >> 6;            // NCH = 64
  const int c  = blockIdx.y & (NCH-1);

  const f32x4* c2p = (const f32x4*)(c2tab + (size_t)e*D_STATE);
  const f32x4 c20=c2p[0], c21=c2p[1], c22=c2p[2], c23=c2p[3];

  f32x4 S0=splat4(0.f), S1=splat4(0.f), S2=splat4(0.f), S3=splat4(0.f);
  const size_t base = ((size_t)b*TT + (size_t)c*CL)*D_MODEL + e;
  const float* xp = x + base;
  const float* dp = delta + base;
  float dts = 0.f;
  #pragma unroll 4
  for (int t = 0; t < CL; ++t) {
    const float dt = dp[(size_t)t*D_MODEL];
    const float xv = xp[(size_t)t*D_MODEL];
    dts += dt;
    const f32x4 u4 = splat4(dt*xv);
    const f32x4 d4 = splat4(dt);
    S0 = exp2v4(c20*d4)*S0 + u4;
    S1 = exp2v4(c21*d4)*S1 + u4;
    S2 = exp2v4(c22*d4)*S2 + u4;
    S3 = exp2v4(c23*d4)*S3 + u4;
  }
  const size_t ci = ((size_t)c*BB + b)*D_MODEL + e;
  dts_out[ci] = dts;
  f32x4* Lp = (f32x4*)&Lc[ci*D_STATE];
  Lp[0]=S0; Lp[1]=S1; Lp[2]=S2; Lp[3]=S3;
}

// ---------------- scan pass 2: in-place exclusive scan over chunks ----------
__global__ __launch_bounds__(256) void scan_pass2_kernel(
    const float* __restrict__ c2tab,
    float* __restrict__ Lc, const float* __restrict__ dts)
{
  const int tid = blockIdx.x * 256 + threadIdx.x;  // < 65536
  const int e = (tid >> 4) & (D_MODEL - 1);
  const int b = tid >> 14;
  const float c2 = c2tab[tid & (D_MODEL*D_STATE - 1)];  // e*16 + s
  float S = 0.f;
  for (int c = 0; c < NCH; ++c) {
    const size_t ce  = ((size_t)c*BB + b)*D_MODEL + e;
    const size_t idx = ce*D_STATE + (tid & 15);
    const float L  = Lc[idx];
    const float Ac = __builtin_amdgcn_exp2f(c2 * dts[ce]);
    Lc[idx] = S;                 // exclusive prefix (chunk initial state)
    S = Ac*S + L;
  }
}

// ---------------- scan pass 3: recompute with carry-in, emit y (bf16) -------
__global__ __launch_bounds__(256) void scan_pass3_kernel(
    const float* __restrict__ x, const float* __restrict__ delta,
    const float* __restrict__ c2tab, const float* __restrict__ b_param,
    const float* __restrict__ Lc, unsigned short* __restrict__ yb)
{
  const int e  = blockIdx.x * 256 + threadIdx.x;
  const int b  = blockIdx.y >> 6;
  const int c  = blockIdx.y & (NCH-1);

  const f32x4* c2p = (const f32x4*)(c2tab + (size_t)e*D_STATE);
  const f32x4 c20=c2p[0], c21=c2p[1], c22=c2p[2], c23=c2p[3];
  const f32x4* bpp = (const f32x4*)(b_param + (size_t)e*D_STATE);
  const f32x4 bp0=bpp[0], bp1=bpp[1], bp2=bpp[2], bp3=bpp[3];

  const size_t ci = ((size_t)c*BB + b)*D_MODEL + e;
  const f32x4* Lp = (const f32x4*)&Lc[ci*D_STATE];
  f32x4 S0=Lp[0], S1=Lp[1], S2=Lp[2], S3=Lp[3];

  const size_t base = ((size_t)b*TT + (size_t)c*CL)*D_MODEL + e;
  const float* xp = x + base;
  const float* dp = delta + base;
  #pragma unroll 4
  for (int t = 0; t < CL; ++t) {
    const float dt = dp[(size_t)t*D_MODEL];
    const float xv = xp[(size_t)t*D_MODEL];
    const f32x4 u4 = splat4(dt*xv);
    const f32x4 d4 = splat4(dt);
    S0 = exp2v4(c20*d4)*S0 + u4;
    S1 = exp2v4(c21*d4)*S1 + u4;
    S2 = exp2v4(c22*d4)*S2 + u4;
    S3 = exp2v4(c23*d4)*S3 + u4;
    const f32x4 yv = bp0*S0 + bp1*S1 + bp2*S2 + bp3*S3;
    const float y = (yv[0]+yv[1]) + (yv[2]+yv[3]);
    yb[base + (size_t)t*D_MODEL] = f2bf(y);
  }
}

// ---------------------------------------------------------------------------
extern "C" void kernel_launch(void* const* d_in, const int* in_sizes, int n_in,
                              void* d_out, int out_size, void* d_ws, size_t ws_size,
                              hipStream_t stream)
{
  (void)in_sizes; (void)n_in; (void)out_size; (void)ws_size;
  const float* x       = (const float*)d_in[0];
  const float* Wd      = (const float*)d_in[1];
  const float* bd      = (const float*)d_in[2];
  const float* a_log   = (const float*)d_in[3];
  const float* b_param = (const float*)d_in[4];
  const float* Wo      = (const float*)d_in[5];
  const float* bo      = (const float*)d_in[6];
  float* out = (float*)d_out;

  // workspace layout (69 MB). Lc/dts alias xb: xb is dead after GEMM1.
  char* ws = (char*)d_ws;
  unsigned short* xb  = (unsigned short*)(ws);              // 16 MB (bf16 x)
  float*          Lc  = (float*)(ws);                       // 16 MB (aliases xb)
  float*          dts = (float*)(ws + 16777216);            //  1 MB
  unsigned short* wdb = (unsigned short*)(ws + 17825792);   //  2 MB
  unsigned short* wob = (unsigned short*)(ws + 19922944);   //  2 MB
  float*          delta = (float*)(ws + 22020096);          // 32 MB
  unsigned short* yb  = (unsigned short*)(ws + 55574528);   // 16 MB

  // c2 table (64 KB) lives at the head of d_out; every scan pass reads it
  // before GEMM2 fully overwrites d_out at the end. Deterministic each call.
  float* c2tab = (float*)d_out;

  prep_c2_kernel<<<(D_MODEL*D_STATE)/256, 256, 0, stream>>>(
      a_log, c2tab, D_MODEL*D_STATE);

  cvt_bf16_kernel<<<1024, 256, 0, stream>>>(x,  xb,  (MM*D_MODEL)/4);
  cvt_bf16_kernel<<<512,  256, 0, stream>>>(Wd, wdb, (D_MODEL*D_MODEL)/4);
  cvt_bf16_kernel<<<512,  256, 0, stream>>>(Wo, wob, (D_MODEL*D_MODEL)/4);

  gemm_bs_kernel<true><<<dim3((MM/512)*(D_MODEL/32)), 512, 0, stream>>>(
      xb, wdb, bd, delta, MM, D_MODEL, D_MODEL);

  scan_pass1_kernel<<<dim3(D_MODEL/256, BB*NCH), 256, 0, stream>>>(
      x, delta, c2tab, Lc, dts);
  scan_pass2_kernel<<<(BB*D_MODEL*D_STATE)/256, 256, 0, stream>>>(
      c2tab, Lc, dts);
  scan_pass3_kernel<<<dim3(D_MODEL/256, BB*NCH), 256, 0, stream>>>(
      x, delta, c2tab, b_param, Lc, yb);

  gemm_bs_kernel<false><<<dim3((MM/512)*(D_MODEL/32)), 512, 0, stream>>>(
      yb, wob, bo, out, MM, D_MODEL, D_MODEL);
}

// Round 8
// 171.396 us; speedup vs baseline: 1.2739x; 1.2739x over previous
//
#include <hip/hip_runtime.h>
#include <stdint.h>

#define D_MODEL 1024
#define D_STATE 16
#define BB 4
#define TT 2048
#define MM (BB*TT)       /* 8192 rows */
#define NCH 64           /* time chunks */
#define CL (TT/NCH)      /* 32 steps per chunk */

typedef __attribute__((ext_vector_type(4))) float f32x4;
typedef __attribute__((ext_vector_type(8))) short short8;

__device__ __forceinline__ unsigned short f2bf(float f) {
  union { float f; uint32_t u; } v; v.f = f;
  uint32_t r = v.u + 0x7FFFu + ((v.u >> 16) & 1u);   // RNE
  return (unsigned short)(r >> 16);
}

__device__ __forceinline__ float softplusf(float v) {
  return v > 20.f ? v : log1pf(expf(v));
}

__device__ __forceinline__ f32x4 splat4(float s) {
  f32x4 r; r[0]=s; r[1]=s; r[2]=s; r[3]=s; return r;
}
__device__ __forceinline__ f32x4 exp2v4(f32x4 v) {
  f32x4 r;
  r[0]=__builtin_amdgcn_exp2f(v[0]);
  r[1]=__builtin_amdgcn_exp2f(v[1]);
  r[2]=__builtin_amdgcn_exp2f(v[2]);
  r[3]=__builtin_amdgcn_exp2f(v[3]);
  return r;
}

// ---------------- f32 -> bf16 conversion (float4 vectorized) ----------------
__global__ __launch_bounds__(256) void cvt_bf16_kernel(
    const float* __restrict__ in, unsigned short* __restrict__ out, int n4)
{
  const float4* in4 = (const float4*)in;
  ushort4* out4 = (ushort4*)out;
  int i = blockIdx.x * blockDim.x + threadIdx.x;
  const int stride = gridDim.x * blockDim.x;
  for (; i < n4; i += stride) {
    float4 v = in4[i];
    ushort4 o;
    o.x = f2bf(v.x); o.y = f2bf(v.y); o.z = f2bf(v.z); o.w = f2bf(v.w);
    out4[i] = o;
  }
}

// ---------------- precompute c2[e][s] = -(softplus(a_log)+1e-4)*log2e -------
__global__ __launch_bounds__(256) void prep_c2_kernel(
    const float* __restrict__ a_log, float* __restrict__ c2tab, int n)
{
  int i = blockIdx.x * 256 + threadIdx.x;
  if (i < n) {
    const float ap = softplusf(a_log[i]) + 1e-4f;
    c2tab[i] = -ap * 1.44269504088896f;
  }
}

__device__ __forceinline__ void glds16(const char* g, char* l) {
  __builtin_amdgcn_global_load_lds(
      (const __attribute__((address_space(1))) void*)g,
      (__attribute__((address_space(3))) void*)l, 16, 0, 0);
}

// ---------------- bf16 GEMM, B^T layout: C[m][n] = sum_k A[m][k]*B[n][k] ----
// R3 schedule + R5 conflict-free LDS:
//   128x128 tile, BK=64, 512 thr / 8 waves (2x4, wave out 64x32),
//   double-buffered LDS (64KB), stage(i+1)-then-vmcnt(4), 2 barriers/iter,
//   2 blocks/CU -> 4 waves/SIMD.
// LDS is FRAGMENT-ORDERED 1KB chunks: chunk s = rowgrp*2 + khalf; lane l of
// chunk s holds X[s16rows + (l&15)][khalf*32 + (l>>4)*8 ..+7]. Staged with
// per-lane GLOBAL source + wave-uniform LDS dest (HW adds lane*16), so
// compute ds_read_b128 at chunkbase + lane*16 is conflict-free by
// construction (verified R5: SQ_LDS_BANK_CONFLICT = 0).
template<bool SOFTPLUS>
__device__ __forceinline__ void stage64(
    const unsigned short* __restrict__ A, const unsigned short* __restrict__ Bm,
    unsigned short* Al, unsigned short* Bl,
    int bm, int bn, int k0, int K, int w, int l)
{
  const int r16 = l & 15;
  const int khb = (l >> 4) * 16;
  #pragma unroll
  for (int ks = 0; ks < 2; ++ks) {
    const char* ga = (const char*)A  + ((size_t)(bm + w*16 + r16)*K + k0 + ks*32)*2 + khb;
    const char* gb = (const char*)Bm + ((size_t)(bn + w*16 + r16)*K + k0 + ks*32)*2 + khb;
    glds16(ga, (char*)Al + (w*2 + ks)*1024);
    glds16(gb, (char*)Bl + (w*2 + ks)*1024);
  }
}

template<bool SOFTPLUS>
__global__ __launch_bounds__(512, 4) void gemm_bt_kernel(
    const unsigned short* __restrict__ A,   // M x K bf16 (row-major)
    const unsigned short* __restrict__ Bm,  // N x K bf16 (row-major, i.e. B^T)
    const float* __restrict__ bias,         // N
    float* __restrict__ C,                  // M x N f32
    int M, int N, int K)
{
  __shared__ __align__(16) unsigned short Al[2][8192];  // 2 x 16KB (16 chunks)
  __shared__ __align__(16) unsigned short Bl[2][8192];  // 2 x 16KB
  const int tid  = threadIdx.x;
  const int lane = tid & 63;
  const int w    = tid >> 6;           // wave 0..7
  const int wr   = w >> 2, wc = w & 3; // 2x4 wave grid, 64x32 out each
  const int r16  = lane & 15, kh = lane >> 4;

  // T1: bijective XCD chunk swizzle (nwg % 8 == 0)
  const int nwg   = gridDim.x;
  const int flat  = blockIdx.x;
  const int newid = (flat & 7) * (nwg >> 3) + (flat >> 3);
  const int bm    = (newid >> 3) * 128;
  const int bn    = (newid & 7) * 128;

  f32x4 acc[4][2] = {};
  const int NT = K >> 6;    // 16

  stage64<SOFTPLUS>(A, Bm, Al[0], Bl[0], bm, bn, 0, K, w, lane);

  for (int i = 0; i < NT; ++i) {
    if (i + 1 < NT) {
      stage64<SOFTPLUS>(A, Bm, Al[(i+1)&1], Bl[(i+1)&1], bm, bn, (i+1)*64, K, w, lane);
      asm volatile("s_waitcnt vmcnt(4)" ::: "memory");  // stage i's 4 loads done
    } else {
      asm volatile("s_waitcnt vmcnt(0)" ::: "memory");
    }
    __builtin_amdgcn_s_barrier();   // stage i visible to all waves

    const char* Ab = (const char*)Al[i & 1] + wr*8192 + lane*16;  // chunk (wr*4+m)*2+ks
    const char* Bb = (const char*)Bl[i & 1] + wc*4096 + lane*16;  // chunk (wc*2+n)*2+ks
    short8 af[4][2], bf[2][2];
    #pragma unroll
    for (int m = 0; m < 4; ++m) {
      af[m][0] = *(const short8*)(Ab + m*2048);
      af[m][1] = *(const short8*)(Ab + m*2048 + 1024);
    }
    #pragma unroll
    for (int n = 0; n < 2; ++n) {
      bf[n][0] = *(const short8*)(Bb + n*2048);
      bf[n][1] = *(const short8*)(Bb + n*2048 + 1024);
    }
    #pragma unroll
    for (int ks = 0; ks < 2; ++ks)
      #pragma unroll
      for (int m = 0; m < 4; ++m)
        #pragma unroll
        for (int n = 0; n < 2; ++n)
          acc[m][n] = __builtin_amdgcn_mfma_f32_16x16x32_bf16(af[m][ks], bf[n][ks], acc[m][n], 0, 0, 0);

    __builtin_amdgcn_s_barrier();   // reads of buf[i&1] retired before overwrite
  }

  // epilogue: row = bm + wr*64 + m*16 + kh*4 + j ; col = bn + wc*32 + n*16 + r16
  #pragma unroll
  for (int n = 0; n < 2; ++n) {
    const int col = bn + wc*32 + n*16 + r16;
    const float bv = bias[col];
    #pragma unroll
    for (int m = 0; m < 4; ++m) {
      #pragma unroll
      for (int j = 0; j < 4; ++j) {
        const int row = bm + wr*64 + m*16 + kh*4 + j;
        float v = acc[m][n][j] + bv;
        if (SOFTPLUS) v = softplusf(v);
        C[(size_t)row*N + col] = v;
      }
    }
  }
}

// ---------------- scan pass 1: per-chunk local state L and sum(dt) ----------
__global__ __launch_bounds__(256) void scan_pass1_kernel(
    const float* __restrict__ x, const float* __restrict__ delta,
    const float* __restrict__ c2tab,
    float* __restrict__ Lc, float* __restrict__ dts_out)
{
  const int e  = blockIdx.x * 256 + threadIdx.x;
  const int b  = blockIdx.y >> 6;            // NCH = 64
  const int c  = blockIdx.y & (NCH-1);

  const f32x4* c2p = (const f32x4*)(c2tab + (size_t)e*D_STATE);
  const f32x4 c20=c2p[0], c21=c2p[1], c22=c2p[2], c23=c2p[3];

  f32x4 S0=splat4(0.f), S1=splat4(0.f), S2=splat4(0.f), S3=splat4(0.f);
  const size_t base = ((size_t)b*TT + (size_t)c*CL)*D_MODEL + e;
  const float* xp = x + base;
  const float* dp = delta + base;
  float dts = 0.f;
  #pragma unroll 4
  for (int t = 0; t < CL; ++t) {
    const float dt = dp[(size_t)t*D_MODEL];
    const float xv = xp[(size_t)t*D_MODEL];
    dts += dt;
    const f32x4 u4 = splat4(dt*xv);
    const f32x4 d4 = splat4(dt);
    S0 = exp2v4(c20*d4)*S0 + u4;
    S1 = exp2v4(c21*d4)*S1 + u4;
    S2 = exp2v4(c22*d4)*S2 + u4;
    S3 = exp2v4(c23*d4)*S3 + u4;
  }
  const size_t ci = ((size_t)c*BB + b)*D_MODEL + e;
  dts_out[ci] = dts;
  f32x4* Lp = (f32x4*)&Lc[ci*D_STATE];
  Lp[0]=S0; Lp[1]=S1; Lp[2]=S2; Lp[3]=S3;
}

// ---------------- scan pass 2: in-place exclusive scan over chunks ----------
__global__ __launch_bounds__(256) void scan_pass2_kernel(
    const float* __restrict__ c2tab,
    float* __restrict__ Lc, const float* __restrict__ dts)
{
  const int tid = blockIdx.x * 256 + threadIdx.x;  // < 65536
  const int e = (tid >> 4) & (D_MODEL - 1);
  const int b = tid >> 14;
  const float c2 = c2tab[tid & (D_MODEL*D_STATE - 1)];  // e*16 + s
  float S = 0.f;
  for (int c = 0; c < NCH; ++c) {
    const size_t ce  = ((size_t)c*BB + b)*D_MODEL + e;
    const size_t idx = ce*D_STATE + (tid & 15);
    const float L  = Lc[idx];
    const float Ac = __builtin_amdgcn_exp2f(c2 * dts[ce]);
    Lc[idx] = S;                 // exclusive prefix (chunk initial state)
    S = Ac*S + L;
  }
}

// ---------------- scan pass 3: recompute with carry-in, emit y (bf16) -------
__global__ __launch_bounds__(256) void scan_pass3_kernel(
    const float* __restrict__ x, const float* __restrict__ delta,
    const float* __restrict__ c2tab, const float* __restrict__ b_param,
    const float* __restrict__ Lc, unsigned short* __restrict__ yb)
{
  const int e  = blockIdx.x * 256 + threadIdx.x;
  const int b  = blockIdx.y >> 6;
  const int c  = blockIdx.y & (NCH-1);

  const f32x4* c2p = (const f32x4*)(c2tab + (size_t)e*D_STATE);
  const f32x4 c20=c2p[0], c21=c2p[1], c22=c2p[2], c23=c2p[3];
  const f32x4* bpp = (const f32x4*)(b_param + (size_t)e*D_STATE);
  const f32x4 bp0=bpp[0], bp1=bpp[1], bp2=bpp[2], bp3=bpp[3];

  const size_t ci = ((size_t)c*BB + b)*D_MODEL + e;
  const f32x4* Lp = (const f32x4*)&Lc[ci*D_STATE];
  f32x4 S0=Lp[0], S1=Lp[1], S2=Lp[2], S3=Lp[3];

  const size_t base = ((size_t)b*TT + (size_t)c*CL)*D_MODEL + e;
  const float* xp = x + base;
  const float* dp = delta + base;
  #pragma unroll 4
  for (int t = 0; t < CL; ++t) {
    const float dt = dp[(size_t)t*D_MODEL];
    const float xv = xp[(size_t)t*D_MODEL];
    const f32x4 u4 = splat4(dt*xv);
    const f32x4 d4 = splat4(dt);
    S0 = exp2v4(c20*d4)*S0 + u4;
    S1 = exp2v4(c21*d4)*S1 + u4;
    S2 = exp2v4(c22*d4)*S2 + u4;
    S3 = exp2v4(c23*d4)*S3 + u4;
    const f32x4 yv = bp0*S0 + bp1*S1 + bp2*S2 + bp3*S3;
    const float y = (yv[0]+yv[1]) + (yv[2]+yv[3]);
    yb[base + (size_t)t*D_MODEL] = f2bf(y);
  }
}

// ---------------------------------------------------------------------------
extern "C" void kernel_launch(void* const* d_in, const int* in_sizes, int n_in,
                              void* d_out, int out_size, void* d_ws, size_t ws_size,
                              hipStream_t stream)
{
  (void)in_sizes; (void)n_in; (void)out_size; (void)ws_size;
  const float* x       = (const float*)d_in[0];
  const float* Wd      = (const float*)d_in[1];
  const float* bd      = (const float*)d_in[2];
  const float* a_log   = (const float*)d_in[3];
  const float* b_param = (const float*)d_in[4];
  const float* Wo      = (const float*)d_in[5];
  const float* bo      = (const float*)d_in[6];
  float* out = (float*)d_out;

  // workspace layout (69 MB). Lc/dts alias xb: xb is dead after GEMM1.
  char* ws = (char*)d_ws;
  unsigned short* xb  = (unsigned short*)(ws);              // 16 MB (bf16 x)
  float*          Lc  = (float*)(ws);                       // 16 MB (aliases xb)
  float*          dts = (float*)(ws + 16777216);            //  1 MB
  unsigned short* wdb = (unsigned short*)(ws + 17825792);   //  2 MB
  unsigned short* wob = (unsigned short*)(ws + 19922944);   //  2 MB
  float*          delta = (float*)(ws + 22020096);          // 32 MB
  unsigned short* yb  = (unsigned short*)(ws + 55574528);   // 16 MB

  // c2 table (64 KB) lives at the head of d_out; every scan pass reads it
  // before GEMM2 fully overwrites d_out at the end. Deterministic each call.
  float* c2tab = (float*)d_out;

  prep_c2_kernel<<<(D_MODEL*D_STATE)/256, 256, 0, stream>>>(
      a_log, c2tab, D_MODEL*D_STATE);

  cvt_bf16_kernel<<<1024, 256, 0, stream>>>(x,  xb,  (MM*D_MODEL)/4);
  cvt_bf16_kernel<<<512,  256, 0, stream>>>(Wd, wdb, (D_MODEL*D_MODEL)/4);
  cvt_bf16_kernel<<<512,  256, 0, stream>>>(Wo, wob, (D_MODEL*D_MODEL)/4);

  gemm_bt_kernel<true><<<dim3((MM/128)*(D_MODEL/128)), 512, 0, stream>>>(
      xb, wdb, bd, delta, MM, D_MODEL, D_MODEL);

  scan_pass1_kernel<<<dim3(D_MODEL/256, BB*NCH), 256, 0, stream>>>(
      x, delta, c2tab, Lc, dts);
  scan_pass2_kernel<<<(BB*D_MODEL*D_STATE)/256, 256, 0, stream>>>(
      c2tab, Lc, dts);
  scan_pass3_kernel<<<dim3(D_MODEL/256, BB*NCH), 256, 0, stream>>>(
      x, delta, c2tab, b_param, Lc, yb);

  gemm_bt_kernel<false><<<dim3((MM/128)*(D_MODEL/128)), 512, 0, stream>>>(
      yb, wob, bo, out, MM, D_MODEL, D_MODEL);
}

// Round 9
// 163.324 us; speedup vs baseline: 1.3369x; 1.0494x over previous
//
#include <hip/hip_runtime.h>
#include <stdint.h>

#define D_MODEL 1024
#define D_STATE 16
#define BB 4
#define TT 2048
#define MM (BB*TT)       /* 8192 rows */
#define NCH 64           /* time chunks */
#define CL (TT/NCH)      /* 32 steps per chunk */

typedef __attribute__((ext_vector_type(4))) float f32x4;
typedef __attribute__((ext_vector_type(8))) short short8;

__device__ __forceinline__ unsigned short f2bf(float f) {
  union { float f; uint32_t u; } v; v.f = f;
  uint32_t r = v.u + 0x7FFFu + ((v.u >> 16) & 1u);   // RNE
  return (unsigned short)(r >> 16);
}

__device__ __forceinline__ float softplusf(float v) {
  return v > 20.f ? v : log1pf(expf(v));
}

__device__ __forceinline__ f32x4 splat4(float s) {
  f32x4 r; r[0]=s; r[1]=s; r[2]=s; r[3]=s; return r;
}
__device__ __forceinline__ f32x4 exp2v4(f32x4 v) {
  f32x4 r;
  r[0]=__builtin_amdgcn_exp2f(v[0]);
  r[1]=__builtin_amdgcn_exp2f(v[1]);
  r[2]=__builtin_amdgcn_exp2f(v[2]);
  r[3]=__builtin_amdgcn_exp2f(v[3]);
  return r;
}

// ---------------- f32 -> bf16 conversion (float4 vectorized) ----------------
__global__ __launch_bounds__(256) void cvt_bf16_kernel(
    const float* __restrict__ in, unsigned short* __restrict__ out, int n4)
{
  const float4* in4 = (const float4*)in;
  ushort4* out4 = (ushort4*)out;
  int i = blockIdx.x * blockDim.x + threadIdx.x;
  const int stride = gridDim.x * blockDim.x;
  for (; i < n4; i += stride) {
    float4 v = in4[i];
    ushort4 o;
    o.x = f2bf(v.x); o.y = f2bf(v.y); o.z = f2bf(v.z); o.w = f2bf(v.w);
    out4[i] = o;
  }
}

// ---------------- precompute c2[e][s] = -(softplus(a_log)+1e-4)*log2e -------
__global__ __launch_bounds__(256) void prep_c2_kernel(
    const float* __restrict__ a_log, float* __restrict__ c2tab, int n)
{
  int i = blockIdx.x * 256 + threadIdx.x;
  if (i < n) {
    const float ap = softplusf(a_log[i]) + 1e-4f;
    c2tab[i] = -ap * 1.44269504088896f;
  }
}

__device__ __forceinline__ void glds16(const char* g, char* l) {
  __builtin_amdgcn_global_load_lds(
      (const __attribute__((address_space(1))) void*)g,
      (__attribute__((address_space(3))) void*)l, 16, 0, 0);
}

// ---------------- bf16 GEMM, 8-phase counted-vmcnt schedule (T3+T4+T5) ------
// 128x128 tile, BK=64, 512 thr / 8 waves (2x4, wave out 64x32), K=1024.
// LDS: 2 buffers x (2 half-slots x 16KB): half-slot = 8 A-chunks + 8 B-chunks
// of 1KB, fragment-ordered (chunk s, lane l <-> X[s*16+(l&15)][(l>>4)*8..+7]),
// conflict-free ds_read at chunkbase+lane*16 (R5-verified, counter=0).
// Half-tile h (tile h>>1, half h&1) = 2 gloads/wave (A chunk w, B chunk w).
// 32 phases; phase = vmcnt(4); barrier; 6 ds_read; STAGE(h=2t+ks+3);
// lgkmcnt(0); setprio(1); 8 MFMA; setprio(0).  vmcnt never drains to 0
// until the tail (t=15: vmcnt(2)/vmcnt(0)) -> 3 half-tiles always in flight.
template<bool SOFTPLUS>
__global__ __launch_bounds__(512, 4) void gemm8p_kernel(
    const unsigned short* __restrict__ A,   // M x K bf16 (row-major)
    const unsigned short* __restrict__ Bm,  // N x K bf16 (row-major, i.e. B^T)
    const float* __restrict__ bias,         // N
    float* __restrict__ C,                  // M x N f32
    int M, int N, int K)
{
  __shared__ __align__(16) char lds[65536];
  const int tid  = threadIdx.x;
  const int lane = tid & 63;
  const int w    = tid >> 6;           // wave 0..7
  const int wr   = w >> 2, wc = w & 3; // 2x4 wave grid, 64x32 out each
  const int r16  = lane & 15, kh = lane >> 4;

  // T1: bijective XCD chunk swizzle (nwg % 8 == 0)
  const int nwg   = gridDim.x;
  const int flat  = blockIdx.x;
  const int newid = (flat & 7) * (nwg >> 3) + (flat >> 3);
  const int bm    = (newid >> 3) * 128;
  const int bn    = (newid & 7) * 128;

  // per-wave staging pointers: lane l stages X[base + w*16 + (l&15)][.. + (l>>4)*8]
  const char* pa = (const char*)A  + ((size_t)(bm + w*16 + r16)*K)*2 + kh*16;
  const char* pb = (const char*)Bm + ((size_t)(bn + w*16 + r16)*K)*2 + kh*16;
  char* la = lds + w*1024;          // A chunk w within a half-slot
  char* lb = lds + 8192 + w*1024;   // B chunk w

  auto STAGE = [&](int h) {   // h = half index 0..31; +64B per half in k
    const int off = (((h >> 1) & 1) << 15) | ((h & 1) << 14);
    glds16(pa + (size_t)h*64, la + off);
    glds16(pb + (size_t)h*64, lb + off);
  };

  STAGE(0); STAGE(1); STAGE(2);   // prologue: 3 half-tiles (6 loads) in flight

  f32x4 acc[4][2] = {};
  const int lane16 = lane*16;
  const int wrA = wr*4096;          // chunk wr*4 .. wr*4+3
  const int wcB = 8192 + wc*2048;   // chunk 8+wc*2 .. +1
  const int NT = K >> 6;            // 16

#define GEMM_PHASE(KS, VM)                                                     \
  {                                                                            \
    asm volatile("s_waitcnt vmcnt(" VM ")" ::: "memory");                      \
    __builtin_amdgcn_s_barrier();                                              \
    const char* fb = lds + ((t & 1) << 15) + ((KS) << 14) + lane16;            \
    short8 a0 = *(const short8*)(fb + wrA);                                    \
    short8 a1 = *(const short8*)(fb + wrA + 1024);                             \
    short8 a2 = *(const short8*)(fb + wrA + 2048);                             \
    short8 a3 = *(const short8*)(fb + wrA + 3072);                             \
    short8 b0 = *(const short8*)(fb + wcB);                                    \
    short8 b1 = *(const short8*)(fb + wcB + 1024);                             \
    const int h = 2*t + (KS) + 3;                                              \
    if (h < 2*NT) STAGE(h);                                                    \
    asm volatile("s_waitcnt lgkmcnt(0)" ::: "memory");                         \
    __builtin_amdgcn_s_setprio(1);                                             \
    acc[0][0] = __builtin_amdgcn_mfma_f32_16x16x32_bf16(a0, b0, acc[0][0],0,0,0); \
    acc[0][1] = __builtin_amdgcn_mfma_f32_16x16x32_bf16(a0, b1, acc[0][1],0,0,0); \
    acc[1][0] = __builtin_amdgcn_mfma_f32_16x16x32_bf16(a1, b0, acc[1][0],0,0,0); \
    acc[1][1] = __builtin_amdgcn_mfma_f32_16x16x32_bf16(a1, b1, acc[1][1],0,0,0); \
    acc[2][0] = __builtin_amdgcn_mfma_f32_16x16x32_bf16(a2, b0, acc[2][0],0,0,0); \
    acc[2][1] = __builtin_amdgcn_mfma_f32_16x16x32_bf16(a2, b1, acc[2][1],0,0,0); \
    acc[3][0] = __builtin_amdgcn_mfma_f32_16x16x32_bf16(a3, b0, acc[3][0],0,0,0); \
    acc[3][1] = __builtin_amdgcn_mfma_f32_16x16x32_bf16(a3, b1, acc[3][1],0,0,0); \
    __builtin_amdgcn_s_setprio(0);                                             \
  }

  for (int t = 0; t < NT - 1; ++t) {
    GEMM_PHASE(0, "4")
    GEMM_PHASE(1, "4")
  }
  {
    const int t = NT - 1;
    GEMM_PHASE(0, "2")
    GEMM_PHASE(1, "0")
  }
#undef GEMM_PHASE

  // epilogue: row = bm + wr*64 + m*16 + kh*4 + j ; col = bn + wc*32 + n*16 + r16
  #pragma unroll
  for (int n = 0; n < 2; ++n) {
    const int col = bn + wc*32 + n*16 + r16;
    const float bv = bias[col];
    #pragma unroll
    for (int m = 0; m < 4; ++m) {
      #pragma unroll
      for (int j = 0; j < 4; ++j) {
        const int row = bm + wr*64 + m*16 + kh*4 + j;
        float v = acc[m][n][j] + bv;
        if (SOFTPLUS) v = softplusf(v);
        C[(size_t)row*N + col] = v;
      }
    }
  }
}

// ---------------- scan pass 1: per-chunk local state L and sum(dt) ----------
__global__ __launch_bounds__(256) void scan_pass1_kernel(
    const float* __restrict__ x, const float* __restrict__ delta,
    const float* __restrict__ c2tab,
    float* __restrict__ Lc, float* __restrict__ dts_out)
{
  const int e  = blockIdx.x * 256 + threadIdx.x;
  const int b  = blockIdx.y >> 6;            // NCH = 64
  const int c  = blockIdx.y & (NCH-1);

  const f32x4* c2p = (const f32x4*)(c2tab + (size_t)e*D_STATE);
  const f32x4 c20=c2p[0], c21=c2p[1], c22=c2p[2], c23=c2p[3];

  f32x4 S0=splat4(0.f), S1=splat4(0.f), S2=splat4(0.f), S3=splat4(0.f);
  const size_t base = ((size_t)b*TT + (size_t)c*CL)*D_MODEL + e;
  const float* xp = x + base;
  const float* dp = delta + base;
  float dts = 0.f;
  #pragma unroll 4
  for (int t = 0; t < CL; ++t) {
    const float dt = dp[(size_t)t*D_MODEL];
    const float xv = xp[(size_t)t*D_MODEL];
    dts += dt;
    const f32x4 u4 = splat4(dt*xv);
    const f32x4 d4 = splat4(dt);
    S0 = exp2v4(c20*d4)*S0 + u4;
    S1 = exp2v4(c21*d4)*S1 + u4;
    S2 = exp2v4(c22*d4)*S2 + u4;
    S3 = exp2v4(c23*d4)*S3 + u4;
  }
  const size_t ci = ((size_t)c*BB + b)*D_MODEL + e;
  dts_out[ci] = dts;
  f32x4* Lp = (f32x4*)&Lc[ci*D_STATE];
  Lp[0]=S0; Lp[1]=S1; Lp[2]=S2; Lp[3]=S3;
}

// ---------------- scan pass 2: in-place exclusive scan over chunks ----------
__global__ __launch_bounds__(256) void scan_pass2_kernel(
    const float* __restrict__ c2tab,
    float* __restrict__ Lc, const float* __restrict__ dts)
{
  const int tid = blockIdx.x * 256 + threadIdx.x;  // < 65536
  const int e = (tid >> 4) & (D_MODEL - 1);
  const int b = tid >> 14;
  const float c2 = c2tab[tid & (D_MODEL*D_STATE - 1)];  // e*16 + s
  float S = 0.f;
  for (int c = 0; c < NCH; ++c) {
    const size_t ce  = ((size_t)c*BB + b)*D_MODEL + e;
    const size_t idx = ce*D_STATE + (tid & 15);
    const float L  = Lc[idx];
    const float Ac = __builtin_amdgcn_exp2f(c2 * dts[ce]);
    Lc[idx] = S;                 // exclusive prefix (chunk initial state)
    S = Ac*S + L;
  }
}

// ---------------- scan pass 3: recompute with carry-in, emit y (bf16) -------
__global__ __launch_bounds__(256) void scan_pass3_kernel(
    const float* __restrict__ x, const float* __restrict__ delta,
    const float* __restrict__ c2tab, const float* __restrict__ b_param,
    const float* __restrict__ Lc, unsigned short* __restrict__ yb)
{
  const int e  = blockIdx.x * 256 + threadIdx.x;
  const int b  = blockIdx.y >> 6;
  const int c  = blockIdx.y & (NCH-1);

  const f32x4* c2p = (const f32x4*)(c2tab + (size_t)e*D_STATE);
  const f32x4 c20=c2p[0], c21=c2p[1], c22=c2p[2], c23=c2p[3];
  const f32x4* bpp = (const f32x4*)(b_param + (size_t)e*D_STATE);
  const f32x4 bp0=bpp[0], bp1=bpp[1], bp2=bpp[2], bp3=bpp[3];

  const size_t ci = ((size_t)c*BB + b)*D_MODEL + e;
  const f32x4* Lp = (const f32x4*)&Lc[ci*D_STATE];
  f32x4 S0=Lp[0], S1=Lp[1], S2=Lp[2], S3=Lp[3];

  const size_t base = ((size_t)b*TT + (size_t)c*CL)*D_MODEL + e;
  const float* xp = x + base;
  const float* dp = delta + base;
  #pragma unroll 4
  for (int t = 0; t < CL; ++t) {
    const float dt = dp[(size_t)t*D_MODEL];
    const float xv = xp[(size_t)t*D_MODEL];
    const f32x4 u4 = splat4(dt*xv);
    const f32x4 d4 = splat4(dt);
    S0 = exp2v4(c20*d4)*S0 + u4;
    S1 = exp2v4(c21*d4)*S1 + u4;
    S2 = exp2v4(c22*d4)*S2 + u4;
    S3 = exp2v4(c23*d4)*S3 + u4;
    const f32x4 yv = bp0*S0 + bp1*S1 + bp2*S2 + bp3*S3;
    const float y = (yv[0]+yv[1]) + (yv[2]+yv[3]);
    yb[base + (size_t)t*D_MODEL] = f2bf(y);
  }
}

// ---------------------------------------------------------------------------
extern "C" void kernel_launch(void* const* d_in, const int* in_sizes, int n_in,
                              void* d_out, int out_size, void* d_ws, size_t ws_size,
                              hipStream_t stream)
{
  (void)in_sizes; (void)n_in; (void)out_size; (void)ws_size;
  const float* x       = (const float*)d_in[0];
  const float* Wd      = (const float*)d_in[1];
  const float* bd      = (const float*)d_in[2];
  const float* a_log   = (const float*)d_in[3];
  const float* b_param = (const float*)d_in[4];
  const float* Wo      = (const float*)d_in[5];
  const float* bo      = (const float*)d_in[6];
  float* out = (float*)d_out;

  // workspace layout (69 MB). Lc/dts alias xb: xb is dead after GEMM1.
  char* ws = (char*)d_ws;
  unsigned short* xb  = (unsigned short*)(ws);              // 16 MB (bf16 x)
  float*          Lc  = (float*)(ws);                       // 16 MB (aliases xb)
  float*          dts = (float*)(ws + 16777216);            //  1 MB
  unsigned short* wdb = (unsigned short*)(ws + 17825792);   //  2 MB
  unsigned short* wob = (unsigned short*)(ws + 19922944);   //  2 MB
  float*          delta = (float*)(ws + 22020096);          // 32 MB
  unsigned short* yb  = (unsigned short*)(ws + 55574528);   // 16 MB

  // c2 table (64 KB) lives at the head of d_out; every scan pass reads it
  // before GEMM2 fully overwrites d_out at the end. Deterministic each call.
  float* c2tab = (float*)d_out;

  prep_c2_kernel<<<(D_MODEL*D_STATE)/256, 256, 0, stream>>>(
      a_log, c2tab, D_MODEL*D_STATE);

  cvt_bf16_kernel<<<1024, 256, 0, stream>>>(x,  xb,  (MM*D_MODEL)/4);
  cvt_bf16_kernel<<<512,  256, 0, stream>>>(Wd, wdb, (D_MODEL*D_MODEL)/4);
  cvt_bf16_kernel<<<512,  256, 0, stream>>>(Wo, wob, (D_MODEL*D_MODEL)/4);

  gemm8p_kernel<true><<<dim3((MM/128)*(D_MODEL/128)), 512, 0, stream>>>(
      xb, wdb, bd, delta, MM, D_MODEL, D_MODEL);

  scan_pass1_kernel<<<dim3(D_MODEL/256, BB*NCH), 256, 0, stream>>>(
      x, delta, c2tab, Lc, dts);
  scan_pass2_kernel<<<(BB*D_MODEL*D_STATE)/256, 256, 0, stream>>>(
      c2tab, Lc, dts);
  scan_pass3_kernel<<<dim3(D_MODEL/256, BB*NCH), 256, 0, stream>>>(
      x, delta, c2tab, b_param, Lc, yb);

  gemm8p_kernel<false><<<dim3((MM/128)*(D_MODEL/128)), 512, 0, stream>>>(
      yb, wob, bo, out, MM, D_MODEL, D_MODEL);
}

// Round 10
// 144.790 us; speedup vs baseline: 1.5080x; 1.1280x over previous
//
#include <hip/hip_runtime.h>
#include <stdint.h>

#define D_MODEL 1024
#define D_STATE 16
#define BB 4
#define TT 2048
#define MM (BB*TT)       /* 8192 rows */
#define NCH 64           /* time chunks */
#define CL (TT/NCH)      /* 32 steps per chunk */

typedef __attribute__((ext_vector_type(4))) float f32x4;
typedef __attribute__((ext_vector_type(8))) short short8;

__device__ __forceinline__ unsigned short f2bf(float f) {
  union { float f; uint32_t u; } v; v.f = f;
  uint32_t r = v.u + 0x7FFFu + ((v.u >> 16) & 1u);   // RNE
  return (unsigned short)(r >> 16);
}

__device__ __forceinline__ float softplusf(float v) {
  return v > 20.f ? v : log1pf(expf(v));
}

__device__ __forceinline__ f32x4 splat4(float s) {
  f32x4 r; r[0]=s; r[1]=s; r[2]=s; r[3]=s; return r;
}
__device__ __forceinline__ f32x4 exp2v4(f32x4 v) {
  f32x4 r;
  r[0]=__builtin_amdgcn_exp2f(v[0]);
  r[1]=__builtin_amdgcn_exp2f(v[1]);
  r[2]=__builtin_amdgcn_exp2f(v[2]);
  r[3]=__builtin_amdgcn_exp2f(v[3]);
  return r;
}

// ---------------- f32 -> bf16 conversion (float4 vectorized) ----------------
__global__ __launch_bounds__(256) void cvt_bf16_kernel(
    const float* __restrict__ in, unsigned short* __restrict__ out, int n4)
{
  const float4* in4 = (const float4*)in;
  ushort4* out4 = (ushort4*)out;
  int i = blockIdx.x * blockDim.x + threadIdx.x;
  const int stride = gridDim.x * blockDim.x;
  for (; i < n4; i += stride) {
    float4 v = in4[i];
    ushort4 o;
    o.x = f2bf(v.x); o.y = f2bf(v.y); o.z = f2bf(v.z); o.w = f2bf(v.w);
    out4[i] = o;
  }
}

// ---------------- precompute c2[e][s] = -(softplus(a_log)+1e-4)*log2e -------
__global__ __launch_bounds__(256) void prep_c2_kernel(
    const float* __restrict__ a_log, float* __restrict__ c2tab, int n)
{
  int i = blockIdx.x * 256 + threadIdx.x;
  if (i < n) {
    const float ap = softplusf(a_log[i]) + 1e-4f;
    c2tab[i] = -ap * 1.44269504088896f;
  }
}

__device__ __forceinline__ void glds16(const char* g, char* l) {
  __builtin_amdgcn_global_load_lds(
      (const __attribute__((address_space(1))) void*)g,
      (__attribute__((address_space(3))) void*)l, 16, 0, 0);
}

// ---------------- bf16 GEMM, B^T layout: C[m][n] = sum_k A[m][k]*B[n][k] ----
// R3 structure (the 54us best: 128x128 tile, BK=64, 512thr/8 waves 2x4,
// double-buffered LDS 64KB, contiguous 1KB/wave staging, stage(i+1) then
// vmcnt(4), 2 barriers/iter, XCD swizzle) + in-row XOR swizzle fixing R3's
// 8-way read conflict while PRESERVING contiguous staging:
//   LDS[row][col] holds global[row][col ^ ((row&7)<<4)]  (col = byte 0..127)
//   - staging: per-lane GLOBAL src XOR; dest linear -> each 4-lane quad still
//     covers one aligned 64B block => coalescing unchanged (16 lines/1KB).
//   - read: colS = colU ^ ((r16&7)<<4): 16-lane groups spread over all 8
//     16B slots / 32 banks at 2 lanes each = 2-way = free (m136).
template<bool SOFTPLUS>
__device__ __forceinline__ void stage64(
    const unsigned short* __restrict__ A, const unsigned short* __restrict__ Bm,
    char* Al, char* Bl, int bm, int bn, int k0, int K, int w, int lane)
{
  const int sub  = ((lane & 7) ^ (lane >> 3)) << 4;   // swizzled col of this lane
  #pragma unroll
  for (int r = 0; r < 2; ++r) {
    const int row = r*64 + w*8 + (lane >> 3);         // tile row this lane stages
    const char* ga = (const char*)A  + ((size_t)(bm + row)*K + k0)*2 + sub;
    const char* gb = (const char*)Bm + ((size_t)(bn + row)*K + k0)*2 + sub;
    char* da = Al + r*8192 + w*1024;                  // wave-uniform dest
    char* db = Bl + r*8192 + w*1024;
    glds16(ga, da);
    glds16(gb, db);
  }
}

template<bool SOFTPLUS>
__global__ __launch_bounds__(512, 4) void gemm_bt_kernel(
    const unsigned short* __restrict__ A,   // M x K bf16 (row-major)
    const unsigned short* __restrict__ Bm,  // N x K bf16 (row-major, i.e. B^T)
    const float* __restrict__ bias,         // N
    float* __restrict__ C,                  // M x N f32
    int M, int N, int K)
{
  __shared__ __align__(16) char Al[2][16384];  // [buf][128 rows][128B]
  __shared__ __align__(16) char Bl[2][16384];
  const int tid  = threadIdx.x;
  const int lane = tid & 63;
  const int w    = tid >> 6;           // wave 0..7
  const int wr   = w >> 2, wc = w & 3; // 2x4 wave grid, 64x32 out each
  const int r16  = lane & 15, kh = lane >> 4;

  // T1: bijective XCD chunk swizzle (nwg % 8 == 0)
  const int nwg   = gridDim.x;
  const int flat  = blockIdx.x;
  const int newid = (flat & 7) * (nwg >> 3) + (flat >> 3);
  const int bm    = (newid >> 3) * 128;
  const int bn    = (newid & 7) * 128;

  // swizzled read columns (per-thread constants)
  const int swz = (r16 & 7) << 4;
  const int c0  = (kh * 16) ^ swz;          // ks = 0
  const int c1  = (64 + kh * 16) ^ swz;     // ks = 1

  f32x4 acc[4][2] = {};
  const int NT = K >> 6;    // 16

  stage64<SOFTPLUS>(A, Bm, Al[0], Bl[0], bm, bn, 0, K, w, lane);

  for (int i = 0; i < NT; ++i) {
    if (i + 1 < NT) {
      stage64<SOFTPLUS>(A, Bm, Al[(i+1)&1], Bl[(i+1)&1], bm, bn, (i+1)*64, K, w, lane);
      asm volatile("s_waitcnt vmcnt(4)" ::: "memory");  // stage i's 4 loads done
    } else {
      asm volatile("s_waitcnt vmcnt(0)" ::: "memory");
    }
    __builtin_amdgcn_s_barrier();   // stage i visible to all waves

    const char* Ab = Al[i & 1] + (wr*64 + r16) * 128;
    const char* Bb = Bl[i & 1] + (wc*32 + r16) * 128;
    short8 af[4][2], bf[2][2];
    #pragma unroll
    for (int m = 0; m < 4; ++m) {
      af[m][0] = *(const short8*)(Ab + m*2048 + c0);
      af[m][1] = *(const short8*)(Ab + m*2048 + c1);
    }
    #pragma unroll
    for (int n = 0; n < 2; ++n) {
      bf[n][0] = *(const short8*)(Bb + n*2048 + c0);
      bf[n][1] = *(const short8*)(Bb + n*2048 + c1);
    }
    #pragma unroll
    for (int ks = 0; ks < 2; ++ks)
      #pragma unroll
      for (int m = 0; m < 4; ++m)
        #pragma unroll
        for (int n = 0; n < 2; ++n)
          acc[m][n] = __builtin_amdgcn_mfma_f32_16x16x32_bf16(af[m][ks], bf[n][ks], acc[m][n], 0, 0, 0);

    __builtin_amdgcn_s_barrier();   // reads of buf[i&1] retired before overwrite
  }

  // epilogue: row = bm + wr*64 + m*16 + kh*4 + j ; col = bn + wc*32 + n*16 + r16
  #pragma unroll
  for (int n = 0; n < 2; ++n) {
    const int col = bn + wc*32 + n*16 + r16;
    const float bv = bias[col];
    #pragma unroll
    for (int m = 0; m < 4; ++m) {
      #pragma unroll
      for (int j = 0; j < 4; ++j) {
        const int row = bm + wr*64 + m*16 + kh*4 + j;
        float v = acc[m][n][j] + bv;
        if (SOFTPLUS) v = softplusf(v);
        C[(size_t)row*N + col] = v;
      }
    }
  }
}

// ---------------- scan pass 1: per-chunk local state L and sum(dt) ----------
__global__ __launch_bounds__(256) void scan_pass1_kernel(
    const float* __restrict__ x, const float* __restrict__ delta,
    const float* __restrict__ c2tab,
    float* __restrict__ Lc, float* __restrict__ dts_out)
{
  const int e  = blockIdx.x * 256 + threadIdx.x;
  const int b  = blockIdx.y >> 6;            // NCH = 64
  const int c  = blockIdx.y & (NCH-1);

  const f32x4* c2p = (const f32x4*)(c2tab + (size_t)e*D_STATE);
  const f32x4 c20=c2p[0], c21=c2p[1], c22=c2p[2], c23=c2p[3];

  f32x4 S0=splat4(0.f), S1=splat4(0.f), S2=splat4(0.f), S3=splat4(0.f);
  const size_t base = ((size_t)b*TT + (size_t)c*CL)*D_MODEL + e;
  const float* xp = x + base;
  const float* dp = delta + base;
  float dts = 0.f;
  #pragma unroll 4
  for (int t = 0; t < CL; ++t) {
    const float dt = dp[(size_t)t*D_MODEL];
    const float xv = xp[(size_t)t*D_MODEL];
    dts += dt;
    const f32x4 u4 = splat4(dt*xv);
    const f32x4 d4 = splat4(dt);
    S0 = exp2v4(c20*d4)*S0 + u4;
    S1 = exp2v4(c21*d4)*S1 + u4;
    S2 = exp2v4(c22*d4)*S2 + u4;
    S3 = exp2v4(c23*d4)*S3 + u4;
  }
  const size_t ci = ((size_t)c*BB + b)*D_MODEL + e;
  dts_out[ci] = dts;
  f32x4* Lp = (f32x4*)&Lc[ci*D_STATE];
  Lp[0]=S0; Lp[1]=S1; Lp[2]=S2; Lp[3]=S3;
}

// ---------------- scan pass 2: in-place exclusive scan over chunks ----------
__global__ __launch_bounds__(256) void scan_pass2_kernel(
    const float* __restrict__ c2tab,
    float* __restrict__ Lc, const float* __restrict__ dts)
{
  const int tid = blockIdx.x * 256 + threadIdx.x;  // < 65536
  const int e = (tid >> 4) & (D_MODEL - 1);
  const int b = tid >> 14;
  const float c2 = c2tab[tid & (D_MODEL*D_STATE - 1)];  // e*16 + s
  float S = 0.f;
  for (int c = 0; c < NCH; ++c) {
    const size_t ce  = ((size_t)c*BB + b)*D_MODEL + e;
    const size_t idx = ce*D_STATE + (tid & 15);
    const float L  = Lc[idx];
    const float Ac = __builtin_amdgcn_exp2f(c2 * dts[ce]);
    Lc[idx] = S;                 // exclusive prefix (chunk initial state)
    S = Ac*S + L;
  }
}

// ---------------- scan pass 3: recompute with carry-in, emit y (bf16) -------
__global__ __launch_bounds__(256) void scan_pass3_kernel(
    const float* __restrict__ x, const float* __restrict__ delta,
    const float* __restrict__ c2tab, const float* __restrict__ b_param,
    const float* __restrict__ Lc, unsigned short* __restrict__ yb)
{
  const int e  = blockIdx.x * 256 + threadIdx.x;
  const int b  = blockIdx.y >> 6;
  const int c  = blockIdx.y & (NCH-1);

  const f32x4* c2p = (const f32x4*)(c2tab + (size_t)e*D_STATE);
  const f32x4 c20=c2p[0], c21=c2p[1], c22=c2p[2], c23=c2p[3];
  const f32x4* bpp = (const f32x4*)(b_param + (size_t)e*D_STATE);
  const f32x4 bp0=bpp[0], bp1=bpp[1], bp2=bpp[2], bp3=bpp[3];

  const size_t ci = ((size_t)c*BB + b)*D_MODEL + e;
  const f32x4* Lp = (const f32x4*)&Lc[ci*D_STATE];
  f32x4 S0=Lp[0], S1=Lp[1], S2=Lp[2], S3=Lp[3];

  const size_t base = ((size_t)b*TT + (size_t)c*CL)*D_MODEL + e;
  const float* xp = x + base;
  const float* dp = delta + base;
  #pragma unroll 4
  for (int t = 0; t < CL; ++t) {
    const float dt = dp[(size_t)t*D_MODEL];
    const float xv = xp[(size_t)t*D_MODEL];
    const f32x4 u4 = splat4(dt*xv);
    const f32x4 d4 = splat4(dt);
    S0 = exp2v4(c20*d4)*S0 + u4;
    S1 = exp2v4(c21*d4)*S1 + u4;
    S2 = exp2v4(c22*d4)*S2 + u4;
    S3 = exp2v4(c23*d4)*S3 + u4;
    const f32x4 yv = bp0*S0 + bp1*S1 + bp2*S2 + bp3*S3;
    const float y = (yv[0]+yv[1]) + (yv[2]+yv[3]);
    yb[base + (size_t)t*D_MODEL] = f2bf(y);
  }
}

// ---------------------------------------------------------------------------
extern "C" void kernel_launch(void* const* d_in, const int* in_sizes, int n_in,
                              void* d_out, int out_size, void* d_ws, size_t ws_size,
                              hipStream_t stream)
{
  (void)in_sizes; (void)n_in; (void)out_size; (void)ws_size;
  const float* x       = (const float*)d_in[0];
  const float* Wd      = (const float*)d_in[1];
  const float* bd      = (const float*)d_in[2];
  const float* a_log   = (const float*)d_in[3];
  const float* b_param = (const float*)d_in[4];
  const float* Wo      = (const float*)d_in[5];
  const float* bo      = (const float*)d_in[6];
  float* out = (float*)d_out;

  // workspace layout (69 MB). Lc/dts alias xb: xb is dead after GEMM1.
  char* ws = (char*)d_ws;
  unsigned short* xb  = (unsigned short*)(ws);              // 16 MB (bf16 x)
  float*          Lc  = (float*)(ws);                       // 16 MB (aliases xb)
  float*          dts = (float*)(ws + 16777216);            //  1 MB
  unsigned short* wdb = (unsigned short*)(ws + 17825792);   //  2 MB
  unsigned short* wob = (unsigned short*)(ws + 19922944);   //  2 MB
  float*          delta = (float*)(ws + 22020096);          // 32 MB
  unsigned short* yb  = (unsigned short*)(ws + 55574528);   // 16 MB

  // c2 table (64 KB) lives at the head of d_out; every scan pass reads it
  // before GEMM2 fully overwrites d_out at the end. Deterministic each call.
  float* c2tab = (float*)d_out;

  prep_c2_kernel<<<(D_MODEL*D_STATE)/256, 256, 0, stream>>>(
      a_log, c2tab, D_MODEL*D_STATE);

  cvt_bf16_kernel<<<1024, 256, 0, stream>>>(x,  xb,  (MM*D_MODEL)/4);
  cvt_bf16_kernel<<<512,  256, 0, stream>>>(Wd, wdb, (D_MODEL*D_MODEL)/4);
  cvt_bf16_kernel<<<512,  256, 0, stream>>>(Wo, wob, (D_MODEL*D_MODEL)/4);

  gemm_bt_kernel<true><<<dim3((MM/128)*(D_MODEL/128)), 512, 0, stream>>>(
      xb, wdb, bd, delta, MM, D_MODEL, D_MODEL);

  scan_pass1_kernel<<<dim3(D_MODEL/256, BB*NCH), 256, 0, stream>>>(
      x, delta, c2tab, Lc, dts);
  scan_pass2_kernel<<<(BB*D_MODEL*D_STATE)/256, 256, 0, stream>>>(
      c2tab, Lc, dts);
  scan_pass3_kernel<<<dim3(D_MODEL/256, BB*NCH), 256, 0, stream>>>(
      x, delta, c2tab, b_param, Lc, yb);

  gemm_bt_kernel<false><<<dim3((MM/128)*(D_MODEL/128)), 512, 0, stream>>>(
      yb, wob, bo, out, MM, D_MODEL, D_MODEL);
}